// Round 8
// baseline (406.486 us; speedup 1.0000x reference)
//
#include <hip/hip_runtime.h>
#include <hip/hip_bf16.h>

#define D 64
#define NUM_LAYERS 4
#define TILE 4096
#define EPT 16          // edges per thread in placeA (256 thr * 16 = TILE)
#define BKMAX 320       // max buckets (N <= 163840)

// ---------------- bucket histogram + scan ----------------

__global__ void bhist_kernel(const int* __restrict__ dst, int* __restrict__ bcnt, int E, int nbk) {
    __shared__ int h[BKMAX];
    for (int i = threadIdx.x; i < nbk; i += blockDim.x) h[i] = 0;
    __syncthreads();
    int stride = gridDim.x * blockDim.x;
    for (int e = blockIdx.x * blockDim.x + threadIdx.x; e < E; e += stride)
        atomicAdd(&h[dst[e] >> 9], 1);
    __syncthreads();
    for (int i = threadIdx.x; i < nbk; i += blockDim.x)
        if (h[i] > 0) atomicAdd(&bcnt[i], h[i]);
}

__global__ __launch_bounds__(512) void bscan_kernel(const int* __restrict__ bcnt,
                                                    int* __restrict__ bstart,
                                                    int* __restrict__ gcur, int nbk, int E) {
    __shared__ int sm[512];
    int t = threadIdx.x;
    int v = (t < nbk) ? bcnt[t] : 0;
    sm[t] = v;
    __syncthreads();
    for (int ofs = 1; ofs < 512; ofs <<= 1) {
        int x = (t >= ofs) ? sm[t - ofs] : 0;
        __syncthreads();
        sm[t] += x;
        __syncthreads();
    }
    int excl = sm[t] - v;
    if (t < nbk) { bstart[t] = excl; gcur[t] = excl; }
    if (t == 0) bstart[nbk] = E;
}

// ---------------- place: two-phase tile-partitioned counting sort ----------------

__global__ __launch_bounds__(256) void placeA_kernel(const int* __restrict__ src,
                                                     const int* __restrict__ dst,
                                                     int* __restrict__ gcur,
                                                     int* __restrict__ mid,
                                                     int E, int nbk) {
    __shared__ int hist[BKMAX];
    __shared__ int gbase[BKMAX];
    int t = threadIdx.x;
    int tile0 = blockIdx.x * TILE;
    for (int i = t; i < nbk; i += 256) hist[i] = 0;
    __syncthreads();

    int p_[EPT];
    int b_[EPT];
    int r_[EPT];
#pragma unroll
    for (int i = 0; i < EPT; ++i) {
        int e = tile0 + i * 256 + t;
        b_[i] = -1;
        if (e < E) {
            int s = src[e], d = dst[e];
            p_[i] = s | ((d & 511) << 18);
            b_[i] = d >> 9;
            r_[i] = atomicAdd(&hist[b_[i]], 1);
        }
    }
    __syncthreads();
    for (int b = t; b < nbk; b += 256) {
        int h = hist[b];
        gbase[b] = (h > 0) ? atomicAdd(&gcur[b], h) : 0;
    }
    __syncthreads();
#pragma unroll
    for (int i = 0; i < EPT; ++i) {
        if (b_[i] >= 0) mid[gbase[b_[i]] + r_[i]] = p_[i];
    }
}

__global__ __launch_bounds__(512) void placeB1_kernel(const int* __restrict__ bstart,
                                                      const int* __restrict__ mid,
                                                      int* __restrict__ row_start,
                                                      float* __restrict__ dis,
                                                      int N, int nbk, int E) {
    __shared__ int degsm[512];
    __shared__ int sc[512];
    int b = blockIdx.x;
    int t = threadIdx.x;
    int node0 = b << 9;
    int lo = bstart[b], hi = bstart[b + 1];
    degsm[t] = 0;
    __syncthreads();
    for (int e = lo + t; e < hi; e += 512)
        atomicAdd(&degsm[(mid[e] >> 18) & 511], 1);
    __syncthreads();
    int d = degsm[t];
    sc[t] = d;
    __syncthreads();
    for (int ofs = 1; ofs < 512; ofs <<= 1) {
        int x = (t >= ofs) ? sc[t - ofs] : 0;
        __syncthreads();
        sc[t] += x;
        __syncthreads();
    }
    int excl = sc[t] - d;
    int node = node0 + t;
    if (node < N) {
        row_start[node] = lo + excl;
        dis[node] = (d > 0) ? rsqrtf((float)d) : 0.0f;
    }
    if (b == nbk - 1 && t == 0) row_start[N] = E;
}

__global__ __launch_bounds__(512) void placeB2_kernel(const int* __restrict__ bstart,
                                                      const int* __restrict__ mid,
                                                      const int* __restrict__ row_start,
                                                      const float* __restrict__ dis,
                                                      int2* __restrict__ csr, int N) {
    __shared__ int cur[512];
    __shared__ float dloc[512];
    int b = blockIdx.x;
    int t = threadIdx.x;
    int node0 = b << 9;
    int node = node0 + t;
    if (node < N) { cur[t] = row_start[node]; dloc[t] = dis[node]; }
    else          { cur[t] = 0; dloc[t] = 0.0f; }
    __syncthreads();
    int lo = bstart[b], hi = bstart[b + 1];
    for (int e = lo + t; e < hi; e += 512) {
        int m = mid[e];
        int l = (m >> 18) & 511;
        int s = m & 0x3FFFF;
        float w = dis[s] * dloc[l];
        int slot = atomicAdd(&cur[l], 1);
        csr[slot] = make_int2(s, __float_as_int(w));
    }
}

// ---------------- propagation ----------------

__global__ void init_kernel(const float* __restrict__ users, const float* __restrict__ items,
                            unsigned* __restrict__ A, int nu_elems, int total2) {
    int i = blockIdx.x * blockDim.x + threadIdx.x;   // bf16x2 pair index
    if (i >= total2) return;
    int base = i * 2;
    float2 v;
    if (base < nu_elems) v = ((const float2*)users)[i];
    else                 v = ((const float2*)items)[(base - nu_elems) >> 1];
    __hip_bfloat16 bx = __float2bfloat16(v.x);
    __hip_bfloat16 by = __float2bfloat16(v.y);
    A[i] = (unsigned)(*reinterpret_cast<unsigned short*>(&bx))
         | ((unsigned)(*reinterpret_cast<unsigned short*>(&by)) << 16);
}

__device__ __forceinline__ float bf_lo(unsigned u) { return __uint_as_float(u << 16); }
__device__ __forceinline__ float bf_hi(unsigned u) { return __uint_as_float(u & 0xffff0000u); }
__device__ __forceinline__ unsigned bf_pack(float x, float y) {
    __hip_bfloat16 bx = __float2bfloat16(x);
    __hip_bfloat16 by = __float2bfloat16(y);
    return (unsigned)(*reinterpret_cast<unsigned short*>(&bx))
         | ((unsigned)(*reinterpret_cast<unsigned short*>(&by)) << 16);
}

// One wave per dst node, 8 lanes per edge: q = lane>>3 picks the edge (8 concurrent),
// c = lane&7 picks the 16B (bf16x8) chunk of the 128B row. 16 edges per iter ->
// 2 independent dwordx4 loads per lane.
template <int FINAL>
__global__ void gather_kernel(const int* __restrict__ row_start,
                              const int2* __restrict__ csr,
                              const uint4* __restrict__ Au,   // input layer, 8 x uint4 per row
                              uint4* __restrict__ Bu,         // output layer (non-final)
                              const float* __restrict__ users, const float* __restrict__ items,
                              const uint4* __restrict__ L1u, const uint4* __restrict__ L2u,
                              float* __restrict__ out,
                              int N, int nu) {
    int node = (blockIdx.x * blockDim.x + threadIdx.x) >> 6;
    if (node >= N) return;
    int lane = threadIdx.x & 63;
    int q = lane >> 3;      // edge slot within group of 8
    int c = lane & 7;       // 16B chunk of row
    int beg = row_start[node];
    int end = row_start[node + 1];
    int deg = end - beg;
    float a0 = 0.f, a1 = 0.f, a2 = 0.f, a3 = 0.f, a4 = 0.f, a5 = 0.f, a6 = 0.f, a7 = 0.f;

    for (int base = 0; base < deg; base += 64) {
        int chunk = min(64, deg - base);
        int   sl = 0;
        float wl = 0.0f;
        if (lane < chunk) {
            int2 e = csr[beg + base + lane];
            sl = e.x;
            wl = __int_as_float(e.y);
        }
        int k = 0;
        for (; k + 16 <= chunk; k += 16) {
            int i0 = k + q, i1 = k + 8 + q;
            int   s0 = __shfl(sl, i0), s1 = __shfl(sl, i1);
            float w0 = __shfl(wl, i0), w1 = __shfl(wl, i1);
            uint4 u0 = Au[(size_t)s0 * 8 + c];
            uint4 u1 = Au[(size_t)s1 * 8 + c];
            a0 += w0 * bf_lo(u0.x); a1 += w0 * bf_hi(u0.x);
            a2 += w0 * bf_lo(u0.y); a3 += w0 * bf_hi(u0.y);
            a4 += w0 * bf_lo(u0.z); a5 += w0 * bf_hi(u0.z);
            a6 += w0 * bf_lo(u0.w); a7 += w0 * bf_hi(u0.w);
            a0 += w1 * bf_lo(u1.x); a1 += w1 * bf_hi(u1.x);
            a2 += w1 * bf_lo(u1.y); a3 += w1 * bf_hi(u1.y);
            a4 += w1 * bf_lo(u1.z); a5 += w1 * bf_hi(u1.z);
            a6 += w1 * bf_lo(u1.w); a7 += w1 * bf_hi(u1.w);
        }
        for (; k < chunk; k += 8) {
            int i0 = k + q;                 // lanes >= chunk carry wl=0 — harmless
            int   s = __shfl(sl, i0);
            float w = __shfl(wl, i0);
            uint4 u = Au[(size_t)s * 8 + c];
            a0 += w * bf_lo(u.x); a1 += w * bf_hi(u.x);
            a2 += w * bf_lo(u.y); a3 += w * bf_hi(u.y);
            a4 += w * bf_lo(u.z); a5 += w * bf_hi(u.z);
            a6 += w * bf_lo(u.w); a7 += w * bf_hi(u.w);
        }
    }

    // reduce the 8 edge streams (lanes differing in bits 3,4,5)
    a0 += __shfl_xor(a0, 8);  a1 += __shfl_xor(a1, 8);
    a2 += __shfl_xor(a2, 8);  a3 += __shfl_xor(a3, 8);
    a4 += __shfl_xor(a4, 8);  a5 += __shfl_xor(a5, 8);
    a6 += __shfl_xor(a6, 8);  a7 += __shfl_xor(a7, 8);
    a0 += __shfl_xor(a0, 16); a1 += __shfl_xor(a1, 16);
    a2 += __shfl_xor(a2, 16); a3 += __shfl_xor(a3, 16);
    a4 += __shfl_xor(a4, 16); a5 += __shfl_xor(a5, 16);
    a6 += __shfl_xor(a6, 16); a7 += __shfl_xor(a7, 16);
    a0 += __shfl_xor(a0, 32); a1 += __shfl_xor(a1, 32);
    a2 += __shfl_xor(a2, 32); a3 += __shfl_xor(a3, 32);
    a4 += __shfl_xor(a4, 32); a5 += __shfl_xor(a5, 32);
    a6 += __shfl_xor(a6, 32); a7 += __shfl_xor(a7, 32);

    if (q == 0) {               // lanes 0..7 hold full sums for elems [8c, 8c+8)
        size_t ro = (size_t)node * 8 + c;
        if (FINAL) {
            uint4 l1 = L1u[ro], l2 = L2u[ro], l3 = Au[ro];   // Au is L3 in final call
            size_t fb = (size_t)node * 16 + 2 * c;
            float4 e0a, e0b;
            if (node < nu) {
                e0a = ((const float4*)users)[fb];
                e0b = ((const float4*)users)[fb + 1];
            } else {
                size_t ib = (size_t)(node - nu) * 16 + 2 * c;
                e0a = ((const float4*)items)[ib];
                e0b = ((const float4*)items)[ib + 1];
            }
            float4 r0, r1;
            r0.x = (e0a.x + bf_lo(l1.x) + bf_lo(l2.x) + bf_lo(l3.x) + a0) * 0.04f;
            r0.y = (e0a.y + bf_hi(l1.x) + bf_hi(l2.x) + bf_hi(l3.x) + a1) * 0.04f;
            r0.z = (e0a.z + bf_lo(l1.y) + bf_lo(l2.y) + bf_lo(l3.y) + a2) * 0.04f;
            r0.w = (e0a.w + bf_hi(l1.y) + bf_hi(l2.y) + bf_hi(l3.y) + a3) * 0.04f;
            r1.x = (e0b.x + bf_lo(l1.z) + bf_lo(l2.z) + bf_lo(l3.z) + a4) * 0.04f;
            r1.y = (e0b.y + bf_hi(l1.z) + bf_hi(l2.z) + bf_hi(l3.z) + a5) * 0.04f;
            r1.z = (e0b.z + bf_lo(l1.w) + bf_lo(l2.w) + bf_lo(l3.w) + a6) * 0.04f;
            r1.w = (e0b.w + bf_hi(l1.w) + bf_hi(l2.w) + bf_hi(l3.w) + a7) * 0.04f;
            ((float4*)out)[fb]     = r0;
            ((float4*)out)[fb + 1] = r1;
        } else {
            uint4 p;
            p.x = bf_pack(a0, a1);
            p.y = bf_pack(a2, a3);
            p.z = bf_pack(a4, a5);
            p.w = bf_pack(a6, a7);
            Bu[ro] = p;
        }
    }
}

// ---------------- launch ----------------

extern "C" void kernel_launch(void* const* d_in, const int* in_sizes, int n_in,
                              void* d_out, int out_size, void* d_ws, size_t ws_size,
                              hipStream_t stream) {
    const float* users = (const float*)d_in[0];
    const float* items = (const float*)d_in[1];
    const int*   eidx  = (const int*)d_in[2];

    const int nu = in_sizes[0] / D;    // 100000
    const int ni = in_sizes[1] / D;    // 50000
    const int N  = nu + ni;            // 150000
    const int E  = in_sizes[2] / 2;    // 2000000
    const int Nf = N * D;              // 9.6M elems
    const int nbk = (N + 511) >> 9;    // 293 buckets

    const int* src = eidx;
    const int* dst = eidx + E;

    char* ws = (char*)d_ws;
    size_t off = 0;
    auto alloc = [&](size_t bytes) {
        char* p = ws + off;
        off += (bytes + 255) & ~(size_t)255;
        return p;
    };
    float* dis       = (float*)alloc((size_t)N * 4);
    int*   row_start = (int*)alloc((size_t)(N + 1) * 4);
    int*   bcnt      = (int*)alloc(BKMAX * 4);
    int*   bstart    = (int*)alloc((BKMAX + 1) * 4);
    int*   gcur      = (int*)alloc(BKMAX * 4);
    int2*  csr       = (int2*)alloc((size_t)E * 8);
    unsigned* A0 = (unsigned*)alloc((size_t)Nf * 2);
    unsigned* L1 = (unsigned*)alloc((size_t)Nf * 2);
    unsigned* L2 = (unsigned*)alloc((size_t)Nf * 2);
    unsigned* L3 = (unsigned*)alloc((size_t)Nf * 2);
    int* mid = (int*)L3;   // alias: mid (E*4B) consumed before L3 is written (gather #3)

    const int B256 = 256;
    auto blocks = [](long long n, int b) { return (int)((n + b - 1) / b); };

    // 1. bucket histogram + bucket scan
    hipMemsetAsync(bcnt, 0, BKMAX * 4, stream);
    bhist_kernel<<<1024, B256, 0, stream>>>(dst, bcnt, E, nbk);
    bscan_kernel<<<1, 512, 0, stream>>>(bcnt, bstart, gcur, nbk, E);

    // 2. place: tile-partition into buckets, per-bucket degree/scan + scatter
    placeA_kernel<<<blocks(E, TILE), B256, 0, stream>>>(src, dst, gcur, mid, E, nbk);
    placeB1_kernel<<<nbk, 512, 0, stream>>>(bstart, mid, row_start, dis, N, nbk, E);
    placeB2_kernel<<<nbk, 512, 0, stream>>>(bstart, mid, row_start, dis, csr, N);

    // 3. init bf16 A0
    init_kernel<<<blocks(Nf / 2, B256), B256, 0, stream>>>(users, items, A0, nu * D, Nf / 2);

    // 4. propagation: L1..L3 bf16; layer 4 fused with final combine -> f32 d_out
    const int ggrid = blocks(N, B256 / 64);
    gather_kernel<0><<<ggrid, B256, 0, stream>>>(row_start, csr, (const uint4*)A0, (uint4*)L1,
                                                 nullptr, nullptr, nullptr, nullptr, nullptr, N, nu);
    gather_kernel<0><<<ggrid, B256, 0, stream>>>(row_start, csr, (const uint4*)L1, (uint4*)L2,
                                                 nullptr, nullptr, nullptr, nullptr, nullptr, N, nu);
    gather_kernel<0><<<ggrid, B256, 0, stream>>>(row_start, csr, (const uint4*)L2, (uint4*)L3,
                                                 nullptr, nullptr, nullptr, nullptr, nullptr, N, nu);
    gather_kernel<1><<<ggrid, B256, 0, stream>>>(row_start, csr, (const uint4*)L3, nullptr,
                                                 users, items, (const uint4*)L1, (const uint4*)L2,
                                                 (float*)d_out, N, nu);
}